// Round 7
// baseline (233.309 us; speedup 1.0000x reference)
//
#include <hip/hip_runtime.h>
#include <hip/hip_bf16.h>
#include <math.h>

#define HH 64
#define WW 64
#define HW 4096
#define LDV 136  // Vl row stride in bf16 elems (272 B, 16B-aligned)

typedef __bf16 bf16x8 __attribute__((ext_vector_type(8)));
typedef float floatx4 __attribute__((ext_vector_type(4)));
typedef unsigned int uint4a __attribute__((ext_vector_type(4)));
typedef unsigned int uint2a __attribute__((ext_vector_type(2)));

// ws layout (byte offsets)
#define WS_Y    0u          // float y[8][128][4096]   16777216 B
#define WS_PSQ  16777216u   // float[256]  (sum, sumsq per channel)
#define WS_XTB  16778240u   // bf16 xtb[8][4096][128]   8388608 B
#define WS_WTB  25166848u   // bf16 wtb[9][128][128]     294912 B
#define WS_OWB  25461760u   // bf16 owb[9][32][128]       73728 B

static __device__ inline ushort f2bf(float f) {
  __hip_bfloat16 h = __float2bfloat16(f);
  return __builtin_bit_cast(ushort, h);
}
static __device__ inline float lo16(unsigned int u) { return __builtin_bit_cast(float, u << 16); }
static __device__ inline float hi16(unsigned int u) { return __builtin_bit_cast(float, u & 0xffff0000u); }

// ---------------- fused prep: x transpose + weight converts + psq zero ------
// grid: [0,4096) transpose tiles; [4096,4672) wtb; [4672,4816) owb; 4816 zero.
__global__ __launch_bounds__(256) void k_prep(const float* __restrict__ x,
                                              const float* __restrict__ w,
                                              const float* __restrict__ ow,
                                              ushort* __restrict__ xtb,
                                              ushort* __restrict__ wtb,
                                              ushort* __restrict__ owb,
                                              float* __restrict__ psq) {
  __shared__ float tile[32][33];
  int bid = blockIdx.x;
  if (bid < 4096) {
    int hw0 = (bid & 127) * 32;
    int c0 = ((bid >> 7) & 3) * 32;
    int b = bid >> 9;
    int col = threadIdx.x & 31, row = threadIdx.x >> 5;
    const float* xb = x + ((size_t)b * 128 + c0) * HW + hw0;
#pragma unroll
    for (int i = 0; i < 32; i += 8)
      tile[row + i][col] = xb[(size_t)(row + i) * HW + col];
    __syncthreads();
    int hw = threadIdx.x >> 3, cq = threadIdx.x & 7;
    ushort* xo = xtb + ((size_t)b * HW + hw0) * 128 + c0;
    unsigned int lo = (unsigned int)f2bf(tile[cq * 4 + 0][hw]) |
                      ((unsigned int)f2bf(tile[cq * 4 + 1][hw]) << 16);
    unsigned int hi = (unsigned int)f2bf(tile[cq * 4 + 2][hw]) |
                      ((unsigned int)f2bf(tile[cq * 4 + 3][hw]) << 16);
    uint2a v2 = (uint2a){lo, hi};
    *(uint2a*)(&xo[(size_t)hw * 128 + cq * 4]) = v2;
  } else if (bid < 4096 + 576) {
    int idx = (bid - 4096) * 256 + threadIdx.x;  // < 147456
    int c = idx & 127, o = (idx >> 7) & 127, k = idx >> 14;
    wtb[idx] = f2bf(w[(o * 128 + c) * 9 + k]);
  } else if (bid < 4096 + 720) {
    int j = (bid - 4672) * 256 + threadIdx.x;  // < 36864
    int c = j & 127, o = (j >> 7) & 31, k = j >> 12;
    float v = (o < 27) ? ow[(o * 128 + c) * 9 + k] : 0.f;
    owb[j] = f2bf(v);
  } else {
    psq[threadIdx.x] = 0.f;
  }
}

// ---------------- fused offset-conv + deformable GEMM + BN partials ---------
// grid (128 half-rows, 8 batch), 256 threads = 4 waves. Tile: 128 o x 32 p.
__global__ __launch_bounds__(256) void k_main(
    const ushort* __restrict__ xtb, const ushort* __restrict__ wtb,
    const ushort* __restrict__ owb, const float* __restrict__ off_b,
    const float* __restrict__ bias, float* __restrict__ y,
    float* __restrict__ psq) {
  __shared__ ushort Vl[32 * LDV];  // 8704 B
  __shared__ float omL[27 * 32];   // 3456 B
  int t = threadIdx.x;
  int lane = t & 63, wv = t >> 6;
  int li = lane & 15, quad = lane >> 4;
  int hr = blockIdx.x;
  int row = hr >> 1, p0b = (hr & 1) * 32;
  int b = blockIdx.y;
  const ushort* xb = xtb + (size_t)b * HW * 128;
  int ch = t & 15;   // 16-B chunk within the 256-B pixel row
  int pq = t >> 4;   // pixel within pass (0..15); passes: pq and pq+16

  // ===== phase 1: offset conv -> omL[27][32] =====
  int mi = wv & 1, ni = wv >> 1;
  floatx4 oacc = (floatx4){0.f, 0.f, 0.f, 0.f};
  uint4a u0, u1;
  auto p1load = [&](int k, int p, uint4a& u) {
    int ky = k / 3, kx = k % 3;
    int ry = row - 1 + ky, cx = p0b + p - 1 + kx;
    bool v = (ry >= 0 && ry < HH && cx >= 0 && cx < WW);
    int idx = v ? (ry * WW + cx) : 0;
    uint4a a = *(const uint4a*)(xb + (size_t)idx * 128 + ch * 8);
    u = v ? a : (uint4a){0u, 0u, 0u, 0u};
  };
  p1load(0, pq, u0);
  p1load(0, pq + 16, u1);
  for (int k = 0; k < 9; ++k) {
    __syncthreads();  // prior iteration's MFMA reads of Vl are done
    *(uint4a*)(&Vl[pq * LDV + ch * 8]) = u0;
    *(uint4a*)(&Vl[(pq + 16) * LDV + ch * 8]) = u1;
    if (k < 8) {  // prefetch k+1 (lands during this k's MFMA)
      p1load(k + 1, pq, u0);
      p1load(k + 1, pq + 16, u1);
    }
    __syncthreads();  // Vl writes visible
#pragma unroll
    for (int ks = 0; ks < 4; ++ks) {
      bf16x8 bfrag = __builtin_bit_cast(bf16x8,
          *(const uint4a*)(&Vl[(ni * 16 + li) * LDV + ks * 32 + quad * 8]));
      bf16x8 afrag = __builtin_bit_cast(bf16x8,
          *(const uint4a*)(&owb[(size_t)(k * 32 + mi * 16 + li) * 128 + ks * 32 + quad * 8]));
      oacc = __builtin_amdgcn_mfma_f32_16x16x32_bf16(afrag, bfrag, oacc, 0, 0, 0);
    }
  }
#pragma unroll
  for (int r = 0; r < 4; ++r) {
    int o = mi * 16 + quad * 4 + r;
    if (o < 27) omL[o * 32 + ni * 16 + li] = oacc[r] + off_b[o];
  }
  __syncthreads();  // omL visible before prep(0) reads it

  // ===== phase 2: deformable sampling + main GEMM =====
  floatx4 macc[2][2];
#pragma unroll
  for (int i = 0; i < 2; ++i)
#pragma unroll
    for (int j = 0; j < 2; ++j) macc[i][j] = (floatx4){0.f, 0.f, 0.f, 0.f};

  float wqA[4], wqB[4];
  int idxA[4], idxB[4];
  uint4a u[8];

  auto prep = [&](int k, int p, float* wq, int* idx4) {
    int ky = k / 3, kx = k % 3;
    float offy = omL[(2 * k) * 32 + p];
    float offx = omL[(2 * k + 1) * 32 + p];
    float mraw = omL[(18 + k) * 32 + p];
    float m = 1.f / (1.f + __expf(-mraw));
    float py = offy + (float)(row - 1 + ky);
    float px = offx + (float)(p0b + p - 1 + kx);
    float y0f = floorf(py), x0f = floorf(px);
    float ly = py - y0f, lx = px - x0f;
    int iy0 = (int)y0f, ix0 = (int)x0f;
    int iy1 = iy0 + 1, ix1 = ix0 + 1;
    float w00 = (1.f - ly) * (1.f - lx) * m, w01 = (1.f - ly) * lx * m;
    float w10 = ly * (1.f - lx) * m, w11 = ly * lx * m;
    if (iy0 < 0 || iy0 > HH - 1) { w00 = 0.f; w01 = 0.f; }
    if (iy1 < 0 || iy1 > HH - 1) { w10 = 0.f; w11 = 0.f; }
    if (ix0 < 0 || ix0 > WW - 1) { w00 = 0.f; w10 = 0.f; }
    if (ix1 < 0 || ix1 > WW - 1) { w01 = 0.f; w11 = 0.f; }
    int cy0 = min(max(iy0, 0), HH - 1), cy1 = min(max(iy1, 0), HH - 1);
    int cx0 = min(max(ix0, 0), WW - 1), cx1 = min(max(ix1, 0), WW - 1);
    idx4[0] = cy0 * WW + cx0;
    idx4[1] = cy0 * WW + cx1;
    idx4[2] = cy1 * WW + cx0;
    idx4[3] = cy1 * WW + cx1;
    wq[0] = w00; wq[1] = w01; wq[2] = w10; wq[3] = w11;
  };
  auto issue = [&]() {
#pragma unroll
    for (int c = 0; c < 4; ++c)
      u[c] = *(const uint4a*)(xb + (size_t)idxA[c] * 128 + ch * 8);
#pragma unroll
    for (int c = 0; c < 4; ++c)
      u[4 + c] = *(const uint4a*)(xb + (size_t)idxB[c] * 128 + ch * 8);
  };

  prep(0, pq, wqA, idxA);
  prep(0, pq + 16, wqB, idxB);
  issue();
  for (int k = 0; k < 9; ++k) {
    __syncthreads();  // prior iteration's MFMA reads of Vl are done
    // hoist A-frag loads: latency drains behind convert+prep VALU below
    const ushort* Arow = &wtb[(size_t)(k * 128 + wv * 32) * 128];
    uint4a af[8];
#pragma unroll
    for (int ks = 0; ks < 4; ++ks) {
      af[ks * 2] = *(const uint4a*)(Arow + (size_t)(li)*128 + ks * 32 + quad * 8);
      af[ks * 2 + 1] = *(const uint4a*)(Arow + (size_t)(16 + li) * 128 + ks * 32 + quad * 8);
    }
    // convert this k's gathers (fp32 math) -> Vl
    {
      uint4a outv;
#pragma unroll
      for (int e = 0; e < 4; ++e) {
        float rlo = wqA[0] * lo16(u[0][e]) + wqA[1] * lo16(u[1][e]) +
                    wqA[2] * lo16(u[2][e]) + wqA[3] * lo16(u[3][e]);
        float rhi = wqA[0] * hi16(u[0][e]) + wqA[1] * hi16(u[1][e]) +
                    wqA[2] * hi16(u[2][e]) + wqA[3] * hi16(u[3][e]);
        outv[e] = (unsigned int)f2bf(rlo) | ((unsigned int)f2bf(rhi) << 16);
      }
      *(uint4a*)(&Vl[pq * LDV + ch * 8]) = outv;
    }
    {
      uint4a outv;
#pragma unroll
      for (int e = 0; e < 4; ++e) {
        float rlo = wqB[0] * lo16(u[4][e]) + wqB[1] * lo16(u[5][e]) +
                    wqB[2] * lo16(u[6][e]) + wqB[3] * lo16(u[7][e]);
        float rhi = wqB[0] * hi16(u[4][e]) + wqB[1] * hi16(u[5][e]) +
                    wqB[2] * hi16(u[6][e]) + wqB[3] * hi16(u[7][e]);
        outv[e] = (unsigned int)f2bf(rlo) | ((unsigned int)f2bf(rhi) << 16);
      }
      *(uint4a*)(&Vl[(pq + 16) * LDV + ch * 8]) = outv;
    }
    if (k < 8) {  // prefetch k+1: gathers fly during this k's MFMA
      prep(k + 1, pq, wqA, idxA);
      prep(k + 1, pq + 16, wqB, idxB);
      issue();
    }
    __syncthreads();  // Vl writes visible
#pragma unroll
    for (int ks = 0; ks < 4; ++ks) {
      bf16x8 b0 = __builtin_bit_cast(bf16x8,
          *(const uint4a*)(&Vl[(li)*LDV + ks * 32 + quad * 8]));
      bf16x8 b1 = __builtin_bit_cast(bf16x8,
          *(const uint4a*)(&Vl[(16 + li) * LDV + ks * 32 + quad * 8]));
      bf16x8 a0 = __builtin_bit_cast(bf16x8, af[ks * 2]);
      bf16x8 a1 = __builtin_bit_cast(bf16x8, af[ks * 2 + 1]);
      macc[0][0] = __builtin_amdgcn_mfma_f32_16x16x32_bf16(a0, b0, macc[0][0], 0, 0, 0);
      macc[0][1] = __builtin_amdgcn_mfma_f32_16x16x32_bf16(a0, b1, macc[0][1], 0, 0, 0);
      macc[1][0] = __builtin_amdgcn_mfma_f32_16x16x32_bf16(a1, b0, macc[1][0], 0, 0, 0);
      macc[1][1] = __builtin_amdgcn_mfma_f32_16x16x32_bf16(a1, b1, macc[1][1], 0, 0, 0);
    }
  }
  // ===== epilogue: bias + y store + BN partials (fused k_stats) =====
#pragma unroll
  for (int ot = 0; ot < 2; ++ot)
#pragma unroll
    for (int r = 0; r < 4; ++r) {
      int o = wv * 32 + ot * 16 + quad * 4 + r;
      float s = 0.f, q = 0.f;
#pragma unroll
      for (int pt = 0; pt < 2; ++pt) {
        int p = p0b + pt * 16 + li;
        float val = macc[ot][pt][r] + bias[o];
        y[((size_t)(b * 128 + o)) * HW + row * 64 + p] = val;
        s += val;
        q += val * val;
      }
#pragma unroll
      for (int off = 8; off >= 1; off >>= 1) {
        s += __shfl_down(s, off, 16);
        q += __shfl_down(q, off, 16);
      }
      if (li == 0) {
        atomicAdd(&psq[o], s);
        atomicAdd(&psq[128 + o], q);
      }
    }
}

// ---------------- normalize + ReLU (scale/shift computed inline) ------------
__global__ __launch_bounds__(256) void k_norm(const float* __restrict__ y,
                                              const float* __restrict__ psq,
                                              const float* __restrict__ gamma,
                                              const float* __restrict__ beta,
                                              float* __restrict__ out) {
  int blk = blockIdx.x;
  int o = (blk >> 2) & 127;
  float s = psq[o], q = psq[128 + o];
  float mean = s * (1.f / 32768.f);
  float var = q * (1.f / 32768.f) - mean * mean;
  float scale = gamma[o] * rsqrtf(var + 1e-5f);
  float shift = beta[o] - mean * scale;
  int i4 = blk * 256 + threadIdx.x;
  float4 v = ((const float4*)y)[i4];
  float4 r;
  r.x = fmaxf(v.x * scale + shift, 0.f);
  r.y = fmaxf(v.y * scale + shift, 0.f);
  r.z = fmaxf(v.z * scale + shift, 0.f);
  r.w = fmaxf(v.w * scale + shift, 0.f);
  ((float4*)out)[i4] = r;
}

extern "C" void kernel_launch(void* const* d_in, const int* in_sizes, int n_in,
                              void* d_out, int out_size, void* d_ws, size_t ws_size,
                              hipStream_t stream) {
  const float* x     = (const float*)d_in[0];
  const float* off_w = (const float*)d_in[1];
  const float* off_b = (const float*)d_in[2];
  const float* w     = (const float*)d_in[3];
  const float* bias  = (const float*)d_in[4];
  const float* gamma = (const float*)d_in[5];
  const float* beta  = (const float*)d_in[6];
  float* out = (float*)d_out;
  char* ws = (char*)d_ws;

  float* y    = (float*)(ws + WS_Y);
  float* psq  = (float*)(ws + WS_PSQ);
  ushort* xtb = (ushort*)(ws + WS_XTB);
  ushort* wtb = (ushort*)(ws + WS_WTB);
  ushort* owb = (ushort*)(ws + WS_OWB);

  k_prep<<<4817, 256, 0, stream>>>(x, w, off_w, xtb, wtb, owb, psq);
  k_main<<<dim3(128, 8), 256, 0, stream>>>(xtb, wtb, owb, off_b, bias, y, psq);
  k_norm<<<4096, 256, 0, stream>>>(y, psq, gamma, beta, out);
}

// Round 8
// 155.319 us; speedup vs baseline: 1.5021x; 1.5021x over previous
//
#include <hip/hip_runtime.h>
#include <hip/hip_bf16.h>
#include <math.h>

#define HH 64
#define WW 64
#define HW 4096
#define LDV 136  // Vl row stride in bf16 elems (272 B, 16B-aligned)

typedef __bf16 bf16x8 __attribute__((ext_vector_type(8)));
typedef float floatx4 __attribute__((ext_vector_type(4)));
typedef unsigned int uint4a __attribute__((ext_vector_type(4)));
typedef unsigned int uint2a __attribute__((ext_vector_type(2)));

// ws layout (byte offsets)
#define WS_Y    0u          // float y[8][128][4096]   16777216 B
#define WS_PSQ  16777216u   // float[256]  (sum, sumsq per channel)
#define WS_XTB  16778240u   // bf16 xtb[8][4096][128]   8388608 B
#define WS_WTB  25166848u   // bf16 wtb[9][128][128]     294912 B
#define WS_OWB  25461760u   // bf16 owb[9][32][128]       73728 B

static __device__ inline ushort f2bf(float f) {
  __hip_bfloat16 h = __float2bfloat16(f);
  return __builtin_bit_cast(ushort, h);
}
static __device__ inline float lo16(unsigned int u) { return __builtin_bit_cast(float, u << 16); }
static __device__ inline float hi16(unsigned int u) { return __builtin_bit_cast(float, u & 0xffff0000u); }

// ---------------- fused prep: x transpose + weight converts + psq zero ------
// grid: [0,4096) transpose tiles; [4096,4672) wtb; [4672,4816) owb; 4816 zero.
__global__ __launch_bounds__(256) void k_prep(const float* __restrict__ x,
                                              const float* __restrict__ w,
                                              const float* __restrict__ ow,
                                              ushort* __restrict__ xtb,
                                              ushort* __restrict__ wtb,
                                              ushort* __restrict__ owb,
                                              float* __restrict__ psq) {
  __shared__ float tile[32][33];
  int bid = blockIdx.x;
  if (bid < 4096) {
    int hw0 = (bid & 127) * 32;
    int c0 = ((bid >> 7) & 3) * 32;
    int b = bid >> 9;
    int col = threadIdx.x & 31, row = threadIdx.x >> 5;
    const float* xb = x + ((size_t)b * 128 + c0) * HW + hw0;
#pragma unroll
    for (int i = 0; i < 32; i += 8)
      tile[row + i][col] = xb[(size_t)(row + i) * HW + col];
    __syncthreads();
    int hw = threadIdx.x >> 3, cq = threadIdx.x & 7;
    ushort* xo = xtb + ((size_t)b * HW + hw0) * 128 + c0;
    unsigned int lo = (unsigned int)f2bf(tile[cq * 4 + 0][hw]) |
                      ((unsigned int)f2bf(tile[cq * 4 + 1][hw]) << 16);
    unsigned int hi = (unsigned int)f2bf(tile[cq * 4 + 2][hw]) |
                      ((unsigned int)f2bf(tile[cq * 4 + 3][hw]) << 16);
    uint2a v2 = (uint2a){lo, hi};
    *(uint2a*)(&xo[(size_t)hw * 128 + cq * 4]) = v2;
  } else if (bid < 4096 + 576) {
    int idx = (bid - 4096) * 256 + threadIdx.x;  // < 147456
    int c = idx & 127, o = (idx >> 7) & 127, k = idx >> 14;
    wtb[idx] = f2bf(w[(o * 128 + c) * 9 + k]);
  } else if (bid < 4096 + 720) {
    int j = (bid - 4672) * 256 + threadIdx.x;  // < 36864
    int c = j & 127, o = (j >> 7) & 31, k = j >> 12;
    float v = (o < 27) ? ow[(o * 128 + c) * 9 + k] : 0.f;
    owb[j] = f2bf(v);
  } else {
    psq[threadIdx.x] = 0.f;
  }
}

// ---------------- fused offset-conv + deformable GEMM ----------------
// grid (128 half-rows, 8 batch), 256 threads = 4 waves. Tile: 128 o x 32 p.
// Double-buffered Vl, ONE barrier per k-step: writes at iter k touch
// Vl[k&1]; a wave writing iter k passed barrier(k-1), which required all
// waves to finish MFMA(k-2) -- the last reader of that buffer.
__global__ __launch_bounds__(256) void k_main(
    const ushort* __restrict__ xtb, const ushort* __restrict__ wtb,
    const ushort* __restrict__ owb, const float* __restrict__ off_b,
    const float* __restrict__ bias, float* __restrict__ y) {
  __shared__ ushort Vl[2][32 * LDV];  // 2 x 8704 B
  __shared__ float omL[27 * 32];      // 3456 B
  int t = threadIdx.x;
  int lane = t & 63, wv = t >> 6;
  int li = lane & 15, quad = lane >> 4;
  int hr = blockIdx.x;
  int row = hr >> 1, p0b = (hr & 1) * 32;
  int b = blockIdx.y;
  const ushort* xb = xtb + (size_t)b * HW * 128;
  int ch = t & 15;   // 16-B chunk within the 256-B pixel row
  int pq = t >> 4;   // pixel within pass (0..15); passes: pq and pq+16

  // ===== phase 1: offset conv -> omL[27][32] =====
  int mi = wv & 1, ni = wv >> 1;
  floatx4 oacc = (floatx4){0.f, 0.f, 0.f, 0.f};
  uint4a u0, u1;
  auto p1load = [&](int k, int p, uint4a& u) {
    int ky = k / 3, kx = k % 3;
    int ry = row - 1 + ky, cx = p0b + p - 1 + kx;
    bool v = (ry >= 0 && ry < HH && cx >= 0 && cx < WW);
    int idx = v ? (ry * WW + cx) : 0;
    uint4a a = *(const uint4a*)(xb + (size_t)idx * 128 + ch * 8);
    u = v ? a : (uint4a){0u, 0u, 0u, 0u};
  };
  p1load(0, pq, u0);
  p1load(0, pq + 16, u1);
  for (int k = 0; k < 9; ++k) {
    *(uint4a*)(&Vl[k & 1][pq * LDV + ch * 8]) = u0;
    *(uint4a*)(&Vl[k & 1][(pq + 16) * LDV + ch * 8]) = u1;
    if (k < 8) {  // prefetch k+1 (lands during this k's MFMA)
      p1load(k + 1, pq, u0);
      p1load(k + 1, pq + 16, u1);
    }
    __syncthreads();  // Vl[k&1] writes visible
#pragma unroll
    for (int ks = 0; ks < 4; ++ks) {
      bf16x8 bfrag = __builtin_bit_cast(bf16x8,
          *(const uint4a*)(&Vl[k & 1][(ni * 16 + li) * LDV + ks * 32 + quad * 8]));
      bf16x8 afrag = __builtin_bit_cast(bf16x8,
          *(const uint4a*)(&owb[(size_t)(k * 32 + mi * 16 + li) * 128 + ks * 32 + quad * 8]));
      oacc = __builtin_amdgcn_mfma_f32_16x16x32_bf16(afrag, bfrag, oacc, 0, 0, 0);
    }
  }
#pragma unroll
  for (int r = 0; r < 4; ++r) {
    int o = mi * 16 + quad * 4 + r;
    if (o < 27) omL[o * 32 + ni * 16 + li] = oacc[r] + off_b[o];
  }
  __syncthreads();  // omL visible; all phase-1 MFMA reads done

  // ===== phase 2: deformable sampling + main GEMM =====
  floatx4 macc[2][2];
#pragma unroll
  for (int i = 0; i < 2; ++i)
#pragma unroll
    for (int j = 0; j < 2; ++j) macc[i][j] = (floatx4){0.f, 0.f, 0.f, 0.f};

  float wqA[4], wqB[4];
  int idxA[4], idxB[4];
  uint4a u[8];

  auto prep = [&](int k, int p, float* wq, int* idx4) {
    int ky = k / 3, kx = k % 3;
    float offy = omL[(2 * k) * 32 + p];
    float offx = omL[(2 * k + 1) * 32 + p];
    float mraw = omL[(18 + k) * 32 + p];
    float m = 1.f / (1.f + __expf(-mraw));
    float py = offy + (float)(row - 1 + ky);
    float px = offx + (float)(p0b + p - 1 + kx);
    float y0f = floorf(py), x0f = floorf(px);
    float ly = py - y0f, lx = px - x0f;
    int iy0 = (int)y0f, ix0 = (int)x0f;
    int iy1 = iy0 + 1, ix1 = ix0 + 1;
    float w00 = (1.f - ly) * (1.f - lx) * m, w01 = (1.f - ly) * lx * m;
    float w10 = ly * (1.f - lx) * m, w11 = ly * lx * m;
    if (iy0 < 0 || iy0 > HH - 1) { w00 = 0.f; w01 = 0.f; }
    if (iy1 < 0 || iy1 > HH - 1) { w10 = 0.f; w11 = 0.f; }
    if (ix0 < 0 || ix0 > WW - 1) { w00 = 0.f; w10 = 0.f; }
    if (ix1 < 0 || ix1 > WW - 1) { w01 = 0.f; w11 = 0.f; }
    int cy0 = min(max(iy0, 0), HH - 1), cy1 = min(max(iy1, 0), HH - 1);
    int cx0 = min(max(ix0, 0), WW - 1), cx1 = min(max(ix1, 0), WW - 1);
    idx4[0] = cy0 * WW + cx0;
    idx4[1] = cy0 * WW + cx1;
    idx4[2] = cy1 * WW + cx0;
    idx4[3] = cy1 * WW + cx1;
    wq[0] = w00; wq[1] = w01; wq[2] = w10; wq[3] = w11;
  };
  auto issue = [&]() {
#pragma unroll
    for (int c = 0; c < 4; ++c)
      u[c] = *(const uint4a*)(xb + (size_t)idxA[c] * 128 + ch * 8);
#pragma unroll
    for (int c = 0; c < 4; ++c)
      u[4 + c] = *(const uint4a*)(xb + (size_t)idxB[c] * 128 + ch * 8);
  };

  prep(0, pq, wqA, idxA);
  prep(0, pq + 16, wqB, idxB);
  issue();
  for (int k = 0; k < 9; ++k) {
    // convert this k's gathers (fp32 math) -> Vl[k&1]
    {
      uint4a outv;
#pragma unroll
      for (int e = 0; e < 4; ++e) {
        float rlo = wqA[0] * lo16(u[0][e]) + wqA[1] * lo16(u[1][e]) +
                    wqA[2] * lo16(u[2][e]) + wqA[3] * lo16(u[3][e]);
        float rhi = wqA[0] * hi16(u[0][e]) + wqA[1] * hi16(u[1][e]) +
                    wqA[2] * hi16(u[2][e]) + wqA[3] * hi16(u[3][e]);
        outv[e] = (unsigned int)f2bf(rlo) | ((unsigned int)f2bf(rhi) << 16);
      }
      *(uint4a*)(&Vl[k & 1][pq * LDV + ch * 8]) = outv;
    }
    {
      uint4a outv;
#pragma unroll
      for (int e = 0; e < 4; ++e) {
        float rlo = wqB[0] * lo16(u[4][e]) + wqB[1] * lo16(u[5][e]) +
                    wqB[2] * lo16(u[6][e]) + wqB[3] * lo16(u[7][e]);
        float rhi = wqB[0] * hi16(u[4][e]) + wqB[1] * hi16(u[5][e]) +
                    wqB[2] * hi16(u[6][e]) + wqB[3] * hi16(u[7][e]);
        outv[e] = (unsigned int)f2bf(rlo) | ((unsigned int)f2bf(rhi) << 16);
      }
      *(uint4a*)(&Vl[k & 1][(pq + 16) * LDV + ch * 8]) = outv;
    }
    if (k < 8) {  // prefetch k+1: gathers fly during barrier wait + MFMA
      prep(k + 1, pq, wqA, idxA);
      prep(k + 1, pq + 16, wqB, idxB);
      issue();
    }
    __syncthreads();  // Vl[k&1] writes visible
    const ushort* Arow = &wtb[(size_t)(k * 128 + wv * 32) * 128];
#pragma unroll
    for (int ks = 0; ks < 4; ++ks) {
      bf16x8 b0 = __builtin_bit_cast(bf16x8,
          *(const uint4a*)(&Vl[k & 1][(li)*LDV + ks * 32 + quad * 8]));
      bf16x8 b1 = __builtin_bit_cast(bf16x8,
          *(const uint4a*)(&Vl[k & 1][(16 + li) * LDV + ks * 32 + quad * 8]));
      bf16x8 a0 = __builtin_bit_cast(bf16x8,
          *(const uint4a*)(Arow + (size_t)(li)*128 + ks * 32 + quad * 8));
      bf16x8 a1 = __builtin_bit_cast(bf16x8,
          *(const uint4a*)(Arow + (size_t)(16 + li) * 128 + ks * 32 + quad * 8));
      macc[0][0] = __builtin_amdgcn_mfma_f32_16x16x32_bf16(a0, b0, macc[0][0], 0, 0, 0);
      macc[0][1] = __builtin_amdgcn_mfma_f32_16x16x32_bf16(a0, b1, macc[0][1], 0, 0, 0);
      macc[1][0] = __builtin_amdgcn_mfma_f32_16x16x32_bf16(a1, b0, macc[1][0], 0, 0, 0);
      macc[1][1] = __builtin_amdgcn_mfma_f32_16x16x32_bf16(a1, b1, macc[1][1], 0, 0, 0);
    }
  }
  // ===== epilogue: bias + y store =====
#pragma unroll
  for (int ot = 0; ot < 2; ++ot)
#pragma unroll
    for (int pt = 0; pt < 2; ++pt)
#pragma unroll
      for (int r = 0; r < 4; ++r) {
        int o = wv * 32 + ot * 16 + quad * 4 + r;
        int p = p0b + pt * 16 + li;
        y[((size_t)(b * 128 + o)) * HW + row * 64 + p] = macc[ot][pt][r] + bias[o];
      }
}

// ---------------- BN partial stats: atomic into psq[256] ----------------
__global__ __launch_bounds__(256) void k_stats(const float* __restrict__ y,
                                               float* __restrict__ psq) {
  int o = blockIdx.x, b = blockIdx.y, t = threadIdx.x;
  const float4* yb = (const float4*)(y + ((size_t)(b * 128 + o)) * HW);
  float s = 0.f, q = 0.f;
#pragma unroll
  for (int i = 0; i < 4; ++i) {
    float4 v = yb[t + i * 256];
    s += v.x + v.y + v.z + v.w;
    q += v.x * v.x + v.y * v.y + v.z * v.z + v.w * v.w;
  }
#pragma unroll
  for (int off = 32; off >= 1; off >>= 1) {
    s += __shfl_down(s, off, 64);
    q += __shfl_down(q, off, 64);
  }
  __shared__ float bs[4], bq[4];
  if ((t & 63) == 0) { bs[t >> 6] = s; bq[t >> 6] = q; }
  __syncthreads();
  if (t == 0) {
    atomicAdd(&psq[o], bs[0] + bs[1] + bs[2] + bs[3]);
    atomicAdd(&psq[128 + o], bq[0] + bq[1] + bq[2] + bq[3]);
  }
}

// ---------------- normalize + ReLU (scale/shift computed inline) ------------
__global__ __launch_bounds__(256) void k_norm(const float* __restrict__ y,
                                              const float* __restrict__ psq,
                                              const float* __restrict__ gamma,
                                              const float* __restrict__ beta,
                                              float* __restrict__ out) {
  int blk = blockIdx.x;
  int o = (blk >> 2) & 127;
  float s = psq[o], q = psq[128 + o];
  float mean = s * (1.f / 32768.f);
  float var = q * (1.f / 32768.f) - mean * mean;
  float scale = gamma[o] * rsqrtf(var + 1e-5f);
  float shift = beta[o] - mean * scale;
  int i4 = blk * 256 + threadIdx.x;
  float4 v = ((const float4*)y)[i4];
  float4 r;
  r.x = fmaxf(v.x * scale + shift, 0.f);
  r.y = fmaxf(v.y * scale + shift, 0.f);
  r.z = fmaxf(v.z * scale + shift, 0.f);
  r.w = fmaxf(v.w * scale + shift, 0.f);
  ((float4*)out)[i4] = r;
}

extern "C" void kernel_launch(void* const* d_in, const int* in_sizes, int n_in,
                              void* d_out, int out_size, void* d_ws, size_t ws_size,
                              hipStream_t stream) {
  const float* x     = (const float*)d_in[0];
  const float* off_w = (const float*)d_in[1];
  const float* off_b = (const float*)d_in[2];
  const float* w     = (const float*)d_in[3];
  const float* bias  = (const float*)d_in[4];
  const float* gamma = (const float*)d_in[5];
  const float* beta  = (const float*)d_in[6];
  float* out = (float*)d_out;
  char* ws = (char*)d_ws;

  float* y    = (float*)(ws + WS_Y);
  float* psq  = (float*)(ws + WS_PSQ);
  ushort* xtb = (ushort*)(ws + WS_XTB);
  ushort* wtb = (ushort*)(ws + WS_WTB);
  ushort* owb = (ushort*)(ws + WS_OWB);

  k_prep<<<4817, 256, 0, stream>>>(x, w, off_w, xtb, wtb, owb, psq);
  k_main<<<dim3(128, 8), 256, 0, stream>>>(xtb, wtb, owb, off_b, bias, y);
  k_stats<<<dim3(128, 8), 256, 0, stream>>>(y, psq);
  k_norm<<<4096, 256, 0, stream>>>(y, psq, gamma, beta, out);
}